// Round 3
// baseline (1677.103 us; speedup 1.0000x reference)
//
#include <hip/hip_runtime.h>

// GRU encoder: B=64, T=256, U=1024, VOCAB=10000. All float tensors are FP32
// on device (per the reference's jnp.float32 — round 1/2 NaNs came from
// misreading f32 buffers as bf16). GEMM runs on bf16 MFMA with RNE-converted
// inputs; the h carry stays exact f32 through d_out.
#define BB 64
#define TT 256
#define UU 1024
#define NG 3072

typedef __attribute__((ext_vector_type(8))) __bf16 bf16x8;
typedef __attribute__((ext_vector_type(4))) float f32x4;

__device__ __forceinline__ unsigned short f2bf(float f) {
    union { unsigned int i; float f; } c; c.f = f;
    unsigned int r = c.i + 0x7FFFu + ((c.i >> 16) & 1u);  // RNE
    return (unsigned short)(r >> 16);
}

union U16x8 { unsigned short us[8]; uint4 u4; };

// ---------------------------------------------------------------------------
// Pack W_rec (f32) into bf16 MFMA B-fragment order.
// slice = cj*4 + kc (cj = unit colgroup 0..63, kc = K-chunk 0..3)
// wpack[(slice*24 + g*8 + s)*64 + lane] = 8 bf16:
//   B[k = kc*256 + s*32 + (lane>>4)*8 + j][n = (cj<<4) + (lane&15)], j=0..7
// Total 6 MB.
// ---------------------------------------------------------------------------
__global__ __launch_bounds__(256) void pack_kernel(
    const float* __restrict__ w_rec,    // (1024, 3072) f32
    uint4* __restrict__ wpack)
{
    const int tid  = threadIdx.x;
    const int kc   = tid >> 6;
    const int lane = tid & 63;
    const int l16  = lane & 15;
    const int quad = lane >> 4;
    const int cj   = blockIdx.x;            // 0..63
    const int colb = (cj << 4) + l16;

    #pragma unroll
    for (int g = 0; g < 3; ++g) {
        #pragma unroll
        for (int s = 0; s < 8; ++s) {
            const int kb = (kc << 8) + (s << 5) + (quad << 3);
            U16x8 c;
            #pragma unroll
            for (int j = 0; j < 8; ++j)
                c.us[j] = f2bf(w_rec[(size_t)(kb + j) * NG + g * UU + colb]);
            wpack[(size_t)(((cj * 4 + kc) * 24) + g * 8 + s) * 64 + lane] = c.u4;
        }
    }
}

// Convert initial hidden state f32 -> bf16 exchange buffer (parity 0).
__global__ __launch_bounds__(256) void seed_kernel(
    const float* __restrict__ hidden,       // (64, 1024) f32
    unsigned short* __restrict__ hbuf)
{
    const int i = blockIdx.x * 256 + threadIdx.x;   // 65536 elements
    hbuf[i] = f2bf(hidden[i]);
}

// ---------------------------------------------------------------------------
// One GRU step. 256 blocks x 256 threads; block = (ri, cj):
// ri = batch rowgroup (4 x 16), cj = unit colgroup (64 x 16).
// Waves K-split (4 x 256). Stream-ordered launches carry all ordering.
// ---------------------------------------------------------------------------
__global__ __launch_bounds__(256) void step_kernel(
    const int* __restrict__ x,              // (64, 256) int32
    const float* __restrict__ hidden,       // (64, 1024) f32
    const float* __restrict__ w_in,         // (10000, 3072) f32
    const float* __restrict__ b_in,         // (3072,) f32
    const float* __restrict__ b_rec,        // (3072,) f32
    const uint4* __restrict__ wpack,        // packed W_rec bf16 frags
    float* __restrict__ out,                // (64,256,1024) + (64,1024) f32
    unsigned short* __restrict__ hbuf,      // ws: 2 x 64 x 1024 bf16 exchange
    int t)
{
    const int tid  = threadIdx.x;
    const int wave = tid >> 6;        // K-chunk 0..3
    const int lane = tid & 63;
    const int l16  = lane & 15;
    const int quad = lane >> 4;

    const int ri   = blockIdx.x >> 6;  // 0..3
    const int cj   = blockIdx.x & 63;  // 0..63
    const int row0 = ri << 4;
    const int col0 = cj << 4;

    __align__(16) __shared__ float red[4][3][64][4];   // 12 KB

    // ---- B-fragments: 24 coalesced dwordx4 loads ----
    const uint4* wp = wpack + (size_t)((cj * 4 + wave) * 24) * 64 + lane;
    uint4 wf[3][8];
    #pragma unroll
    for (int g = 0; g < 3; ++g)
        #pragma unroll
        for (int s = 0; s < 8; ++s)
            wf[g][s] = wp[(g * 8 + s) * 64];

    // ---- A from bf16 exchange buffer, parity t&1 ----
    const unsigned short* arow = hbuf + (size_t)(t & 1) * (BB * UU)
                               + (size_t)(row0 + l16) * UU + (wave << 8) + (quad << 3);

    f32x4 acc0 = {0.f, 0.f, 0.f, 0.f};
    f32x4 acc1 = {0.f, 0.f, 0.f, 0.f};
    f32x4 acc2 = {0.f, 0.f, 0.f, 0.f};
    #pragma unroll
    for (int s = 0; s < 8; ++s) {
        const uint4 av = *(const uint4*)(arow + (s << 5));
        const bf16x8 a = __builtin_bit_cast(bf16x8, av);
        acc0 = __builtin_amdgcn_mfma_f32_16x16x32_bf16(
            a, __builtin_bit_cast(bf16x8, wf[0][s]), acc0, 0, 0, 0);
        acc1 = __builtin_amdgcn_mfma_f32_16x16x32_bf16(
            a, __builtin_bit_cast(bf16x8, wf[1][s]), acc1, 0, 0, 0);
        acc2 = __builtin_amdgcn_mfma_f32_16x16x32_bf16(
            a, __builtin_bit_cast(bf16x8, wf[2][s]), acc2, 0, 0, 0);
    }

    // ---- cross-wave K reduction through LDS ----
    *(f32x4*)&red[wave][0][lane][0] = acc0;
    *(f32x4*)&red[wave][1][lane][0] = acc1;
    *(f32x4*)&red[wave][2][lane][0] = acc2;
    __syncthreads();

    // ---- per-thread gate element (em = batch row, en = unit col) ----
    const int em = tid >> 4;
    const int en = tid & 15;
    const int gb = row0 + em;
    const int gu = col0 + en;
    // C/D layout (col=lane&15, row=(lane>>4)*4+reg) -> source lane/reg
    const int rl = ((em >> 2) << 4) | en;
    const int rr = em & 3;

    const float rz = red[0][0][rl][rr] + red[1][0][rl][rr]
                   + red[2][0][rl][rr] + red[3][0][rl][rr];
    const float rrv = red[0][1][rl][rr] + red[1][1][rl][rr]
                    + red[2][1][rl][rr] + red[3][1][rl][rr];
    const float rh = red[0][2][rl][rr] + red[1][2][rl][rr]
                   + red[2][2][rl][rr] + red[3][2][rl][rr];

    // ---- embedding gather + biases (all f32) ----
    const int xv = x[gb * TT + t];
    const size_t wrow = (size_t)xv * NG;
    const float wz = w_in[wrow + gu];
    const float wr = w_in[wrow + UU + gu];
    const float wh = w_in[wrow + 2 * UU + gu];

    const float bz  = b_in[gu]      + b_rec[gu];
    const float br  = b_in[UU + gu] + b_rec[UU + gu];
    const float bih = b_in[2 * UU + gu];
    const float brh = b_rec[2 * UU + gu];

    // exact f32 h carry: h_{t-1} lives in out[b][t-1][u]
    const float h_prev = (t == 0) ? hidden[gb * UU + gu]
                                  : out[((size_t)gb * TT + (t - 1)) * UU + gu];

    const float z  = 1.f / (1.f + expf(-(wz + rz + bz)));
    const float r  = 1.f / (1.f + expf(-(wr + rrv + br)));
    const float hh = tanhf(wh + bih + r * (rh + brh));
    const float hn = z * h_prev + (1.f - z) * hh;

    out[((size_t)gb * TT + t) * UU + gu] = hn;
    hbuf[(size_t)((t + 1) & 1) * (BB * UU) + gb * UU + gu] = f2bf(hn);

    if (t == TT - 1)
        out[(size_t)BB * TT * UU + (size_t)gb * UU + gu] = hn;
}

extern "C" void kernel_launch(void* const* d_in, const int* in_sizes, int n_in,
                              void* d_out, int out_size, void* d_ws, size_t ws_size,
                              hipStream_t stream) {
    const int* x        = (const int*)d_in[0];
    const float* hidden = (const float*)d_in[1];
    const float* w_in   = (const float*)d_in[2];
    const float* w_rec  = (const float*)d_in[3];
    const float* b_in   = (const float*)d_in[4];
    const float* b_rec  = (const float*)d_in[5];
    float* out          = (float*)d_out;

    unsigned char* ws = (unsigned char*)d_ws;
    uint4* wpack         = (uint4*)ws;                       // 6 MB
    unsigned short* hbuf = (unsigned short*)(ws + 6291456);  // 256 KB (needs ws >= 6.3 MB)

    pack_kernel<<<64, 256, 0, stream>>>(w_rec, wpack);
    seed_kernel<<<256, 256, 0, stream>>>(hidden, hbuf);
    for (int t = 0; t < TT; ++t)
        step_kernel<<<256, 256, 0, stream>>>(x, hidden, w_in, b_in, b_rec,
                                             wpack, out, hbuf, t);
}